// Round 1
// baseline (490.108 us; speedup 1.0000x reference)
//
#include <hip/hip_runtime.h>

#define DIM 100

typedef _Float16 half8 __attribute__((ext_vector_type(8)));
typedef float floatx4 __attribute__((ext_vector_type(4)));

// MFMA fragment planes: [0]=Ur, [1]=Ui, [2]=-Ui (diag phase layer applied).
// Tile (it,kt) covers U rows [it*16,it*16+16) x cols [kt*32,kt*32+32),
// zero-padded past 100. Element j of lane L in tile (it,kt)
//   = plane[it*16+(L&15)][kt*32+(L>>4)*8+j].
// Serves BOTH stage-1 A-fragments and stage-2 B-fragments.
__device__ half8 g_frag[3][7 * 4 * 64];

// ---------------------------------------------------------------------------
// Kernel 1: build U = D * T_K ... T_1 (Clements mesh scan) + pack fragments.
// 4 blocks x 512. Block b owns U columns [32b, 32b+32) (block 3: only 96..99
// real; extra columns carry zeros). Columns evolve independently under
// row-pair Givens updates, so each block scans its slice in LDS
// (100x32 float2 = 25.6 KB). All 4950 trig values precomputed ONCE into
// per-thread registers (k = t + 512*j), staged per layer into a 50-entry LDS
// buffer -> no transcendentals inside the scan. After the scan, block b packs
// g_frag tile column kt = b directly from LDS (pack kernel eliminated).
// ---------------------------------------------------------------------------
__global__ __launch_bounds__(512) void build_U_kernel(
    const float* __restrict__ theta, const float* __restrict__ phi,
    const float* __restrict__ dphase) {
  __shared__ float2 U[DIM][32];
  __shared__ float4 Strig[50];  // current layer: cos(th), sin(th), cos(ph), sin(ph)
  const int t = threadIdx.x;
  const int c0 = blockIdx.x * 32;

  // phase A: per-thread trig precompute (4950 pairs over 512 threads)
  float4 myTrig[10];
#pragma unroll
  for (int j = 0; j < 10; ++j) {
    int k = t + 512 * j;
    if (k < 4950) {
      float th = theta[k];
      float ph = phi[k];
      myTrig[j] = make_float4(cosf(th), sinf(th), cosf(ph), sinf(ph));
    }
  }

  for (int idx = t; idx < DIM * 32; idx += 512) {
    int i = idx >> 5, c = idx & 31;
    U[i][c] = make_float2((i == c0 + c) ? 1.0f : 0.0f, 0.0f);
  }
  __syncthreads();

  for (int layer = 0; layer < DIM; ++layer) {
    const int start = layer & 1;
    const int npairs = 50 - start;
    const int base = (layer >> 1) * 99 + start * 50;
    // stage this layer's trig from registers into LDS
#pragma unroll
    for (int j = 0; j < 10; ++j) {
      int rel = t + 512 * j - base;
      if (rel >= 0 && rel < npairs) Strig[rel] = myTrig[j];
    }
    __syncthreads();
    for (int w = t; w < npairs * 32; w += 512) {
      const int p = w >> 5;
      const int c = w & 31;
      const int m = start + 2 * p;
      const int n = m + 1;
      const float4 tg = Strig[p];
      const float cth = tg.x, sth = tg.y, cp = tg.z, sp = tg.w;
      const float2 rm = U[m][c];
      const float2 rn = U[n][c];
      const float ar = cp * rm.x - sp * rm.y;  // (e^{i ph} * rm).re
      const float ai = cp * rm.y + sp * rm.x;  // (e^{i ph} * rm).im
      U[m][c] = make_float2(cth * ar - sth * rn.x, cth * ai - sth * rn.y);
      U[n][c] = make_float2(sth * ar + cth * rn.x, sth * ai + cth * rn.y);
    }
    __syncthreads();
  }

  // epilogue: apply diag phase and pack this block's g_frag tile (kt = blockIdx.x).
  // 3 planes x 7 it-tiles x 64 lanes = 1344 items.
  const int kt = blockIdx.x;
  for (int idx = t; idx < 3 * 7 * 64; idx += 512) {
    int plane = idx / 448;
    int rem = idx - plane * 448;
    int ln = rem & 63;
    int it = rem >> 6;
    int row = it * 16 + (ln & 15);
    int cl = (ln >> 4) * 8;  // local col base within the 32-wide tile
    float cd = 0.f, sd = 0.f;
    if (row < DIM) {
      float d = dphase[row];
      cd = cosf(d);
      sd = sinf(d);
    }
    half8 h;
#pragma unroll
    for (int j = 0; j < 8; ++j) {
      int c = cl + j;
      float v = 0.f;
      if (row < DIM && (c0 + c) < DIM) {
        float2 u = U[row][c];
        float re = cd * u.x - sd * u.y;
        float im = cd * u.y + sd * u.x;
        v = (plane == 0) ? re : ((plane == 1) ? im : -im);
      }
      h[j] = (_Float16)v;
    }
    g_frag[plane][(it * 4 + kt) * 64 + ln] = h;
  }
}

// ---------------------------------------------------------------------------
// Kernel 2: per batch b (one block, 4 waves):
//   Tr = Ur·Xr - Ui·Xi ; Ti = Ui·Xr + Ur·Xi ; out_re = Tr·Ur^T + Ti·Ui^T
// as 16x16x32 f16 MFMAs, M=N=112 (7 tiles), K=256 (two 128-planes).
// Single LDS buffer S = [112][136] f16 (30464 B) serialized through 4 roles:
//   Xr^T -> (stage-1 kt 0..3) -> Xi^T -> (stage-1 kt 4..7)
//   -> A2r = Tr -> (stage-2 kt2 0..3) -> A2i = Ti -> (stage-2 kt2 4..7).
// Halving LDS (60928 -> 30464 B) lifts occupancy from 2 to 4 blocks/CU
// (VGPR-capped at 4 waves/SIMD via __launch_bounds__(256,4)).
// Pad invariant: S is zeroed ONCE; X stores only touch [0,100)x[0,104),
// A2 stores only [0,112)x[0,112), so cols [104,128) resp. [112,128) read by
// the MFMA fragments stay zero for the whole kernel (no NaN-from-garbage).
// Wave w owns M-tiles {2w, 2w+1} (tile 7 skipped).
// ---------------------------------------------------------------------------
__global__ __launch_bounds__(256, 4) void transform_kernel(
    const float* __restrict__ xre, const float* __restrict__ xim,
    float* __restrict__ out) {
  __shared__ __align__(16) _Float16 S[15232];  // [112][136] = 30,464 B
  const int tid = threadIdx.x;
  const int wave = tid >> 6;
  const int lane = tid & 63;
  const int quad = lane >> 4;
  const int l16 = lane & 15;
  const int b = blockIdx.x;
  const float* __restrict__ Xre = xre + (size_t)b * (DIM * DIM);
  const float* __restrict__ Xim = xim + (size_t)b * (DIM * DIM);

  // ---- phase 0: zero S once (pad regions rely on staying zero) ----
  {
    int4 z = make_int4(0, 0, 0, 0);
    int4* p = (int4*)S;
    for (int i = tid; i < 15232 * 2 / 16; i += 256) p[i] = z;
  }
  __syncthreads();

  const int m0t = wave * 2;
  floatx4 accR[2][7], accI[2][7];
  const floatx4 zz = {0.f, 0.f, 0.f, 0.f};
#pragma unroll
  for (int a = 0; a < 2; ++a)
#pragma unroll
    for (int n = 0; n < 7; ++n) {
      accR[a][n] = zz;
      accI[a][n] = zz;
    }

  // ---- stage 1, one X plane at a time through S ----
#pragma unroll
  for (int pl = 0; pl < 2; ++pl) {
    const float* __restrict__ Xp = pl ? Xim : Xre;
    // load X^T plane: item g -> (k-octet o, col n). Lane holds fixed n,
    // 8 consecutive k: 8 coalesced dword loads, one b128 LDS write.
    // b128 write bank-group = (n + o) mod 8 -> conflict-free.
    for (int g = tid; g < 1300; g += 256) {
      int o = g / 100;
      int n = g - o * 100;
      int k0 = o * 8;
      half8 h;
#pragma unroll
      for (int j = 0; j < 8; ++j) {
        int k = k0 + j;
        float v = (k < DIM) ? Xp[k * DIM + n] : 0.f;
        h[j] = (_Float16)v;
      }
      *(half8*)&S[n * 136 + k0] = h;
    }
    __syncthreads();

    const half8* __restrict__ frR = pl ? g_frag[2] : g_frag[0];  // [Ur | -Ui]
    const half8* __restrict__ frI = pl ? g_frag[0] : g_frag[1];  // [Ui |  Ur]
#pragma unroll
    for (int ktm = 0; ktm < 4; ++ktm) {
      half8 aR[2], aI[2];
#pragma unroll
      for (int mtl = 0; mtl < 2; ++mtl) {
        int mt = m0t + mtl;
        if (mt < 7) {
          int fi = (mt * 4 + ktm) * 64 + lane;
          aR[mtl] = frR[fi];
          aI[mtl] = frI[fi];
        }
      }
#pragma unroll
      for (int nt = 0; nt < 7; ++nt) {
        half8 bf =
            *(const half8*)&S[(nt * 16 + l16) * 136 + ktm * 32 + quad * 8];
#pragma unroll
        for (int mtl = 0; mtl < 2; ++mtl) {
          if (m0t + mtl < 7) {
            accR[mtl][nt] = __builtin_amdgcn_mfma_f32_16x16x32_f16(
                aR[mtl], bf, accR[mtl][nt], 0, 0, 0);
            accI[mtl][nt] = __builtin_amdgcn_mfma_f32_16x16x32_f16(
                aI[mtl], bf, accI[mtl][nt], 0, 0, 0);
          }
        }
      }
    }
    __syncthreads();  // all reads of this plane done before S is overwritten
  }

  // ---- stage 2, one T half at a time through S ----
  floatx4 acc2[2][7];
#pragma unroll
  for (int a = 0; a < 2; ++a)
#pragma unroll
    for (int n = 0; n < 7; ++n) acc2[a][n] = zz;

#pragma unroll
  for (int h = 0; h < 2; ++h) {
    // write T-half into S as A2[m][n'] (h=0: Tr from accR, h=1: Ti from accI)
#pragma unroll
    for (int mtl = 0; mtl < 2; ++mtl) {
      int mt = m0t + mtl;
      if (mt < 7) {
        int row0 = mt * 16 + quad * 4;
#pragma unroll
        for (int nt = 0; nt < 7; ++nt) {
          int c = nt * 16 + l16;
#pragma unroll
          for (int r = 0; r < 4; ++r) {
            float v = h ? accI[mtl][nt][r] : accR[mtl][nt][r];
            S[(row0 + r) * 136 + c] = (_Float16)v;
          }
        }
      }
    }
    __syncthreads();

    const half8* __restrict__ frB = h ? g_frag[1] : g_frag[0];  // Ur^T / Ui^T
#pragma unroll
    for (int mtl = 0; mtl < 2; ++mtl) {
      int mt = m0t + mtl;
      if (mt >= 7) continue;
      half8 a2f[4];
#pragma unroll
      for (int kt2 = 0; kt2 < 4; ++kt2)
        a2f[kt2] =
            *(const half8*)&S[(mt * 16 + l16) * 136 + kt2 * 32 + quad * 8];
#pragma unroll
      for (int nt = 0; nt < 7; ++nt) {
#pragma unroll
        for (int kt2 = 0; kt2 < 4; ++kt2) {
          acc2[mtl][nt] = __builtin_amdgcn_mfma_f32_16x16x32_f16(
              a2f[kt2], frB[(nt * 4 + kt2) * 64 + lane], acc2[mtl][nt], 0, 0,
              0);
        }
      }
    }
    if (h == 0) __syncthreads();  // stage-2a reads done before Ti overwrites S
  }

  // ---- epilogue: real part only, guarded to 100x100 ----
  float* outb = out + (size_t)b * (DIM * DIM);
#pragma unroll
  for (int mtl = 0; mtl < 2; ++mtl) {
    int mt = m0t + mtl;
    if (mt >= 7) continue;
#pragma unroll
    for (int nt = 0; nt < 7; ++nt) {
      int c = nt * 16 + l16;
      if (c < DIM) {
#pragma unroll
        for (int r = 0; r < 4; ++r) {
          int row = mt * 16 + quad * 4 + r;
          if (row < DIM) outb[row * DIM + c] = acc2[mtl][nt][r];
        }
      }
    }
  }
}

extern "C" void kernel_launch(void* const* d_in, const int* in_sizes, int n_in,
                              void* d_out, int out_size, void* d_ws,
                              size_t ws_size, hipStream_t stream) {
  const float* xre = (const float*)d_in[0];
  const float* xim = (const float*)d_in[1];
  const float* theta = (const float*)d_in[2];
  const float* phi = (const float*)d_in[3];
  const float* dphase = (const float*)d_in[4];
  float* out = (float*)d_out;
  (void)d_ws; (void)ws_size; (void)out_size; (void)n_in;

  hipLaunchKernelGGL(build_U_kernel, dim3(4), dim3(512), 0, stream, theta, phi,
                     dphase);
  const int B = in_sizes[0] / (DIM * DIM);  // 2048
  hipLaunchKernelGGL(transform_kernel, dim3(B), dim3(256), 0, stream, xre, xim,
                     out);
}

// Round 2
// 489.715 us; speedup vs baseline: 1.0008x; 1.0008x over previous
//
#include <hip/hip_runtime.h>

#define DIM 100

typedef _Float16 half8 __attribute__((ext_vector_type(8)));
typedef float floatx4 __attribute__((ext_vector_type(4)));

// MFMA fragment planes: [0]=Ur, [1]=Ui, [2]=-Ui (diag phase layer applied).
// Tile (it,kt) covers U rows [it*16,it*16+16) x cols [kt*32,kt*32+32),
// zero-padded past 100. Element j of lane L in tile (it,kt)
//   = plane[it*16+(L&15)][kt*32+(L>>4)*8+j].
// Serves BOTH stage-1 A-fragments and stage-2 B-fragments.
__device__ half8 g_frag[3][7 * 4 * 64];

// ---------------------------------------------------------------------------
// Kernel 1: build U = D * T_K ... T_1 (Clements mesh scan) + pack fragments.
// 4 blocks x 512. Block b owns U columns [32b, 32b+32) (block 3: only 96..99
// real; extra columns carry zeros). Columns evolve independently under
// row-pair Givens updates, so each block scans its slice in LDS
// (100x32 float2 = 25.6 KB). All 4950 trig values precomputed ONCE into
// per-thread registers (k = t + 512*j). Per-layer trig is staged into a
// DOUBLE-BUFFERED 50-entry LDS buffer: layer L+1 is staged while layer L
// updates, so the scan needs only ONE barrier per layer (the scan is a
// 100-deep serial chain; per-layer latency is everything). After the scan,
// block b packs g_frag tile column kt = b directly from LDS.
// ---------------------------------------------------------------------------
__global__ __launch_bounds__(512) void build_U_kernel(
    const float* __restrict__ theta, const float* __restrict__ phi,
    const float* __restrict__ dphase) {
  __shared__ float2 U[DIM][32];
  __shared__ float4 Strig[2][50];  // cos(th), sin(th), cos(ph), sin(ph)
  const int t = threadIdx.x;
  const int c0 = blockIdx.x * 32;

  // phase A: per-thread trig precompute (4950 pairs over 512 threads)
  float4 myTrig[10];
#pragma unroll
  for (int j = 0; j < 10; ++j) {
    int k = t + 512 * j;
    if (k < 4950) {
      float th = theta[k];
      float ph = phi[k];
      myTrig[j] = make_float4(cosf(th), sinf(th), cosf(ph), sinf(ph));
    }
  }

  // stage layer 0 (pairs k = 0..49 live in myTrig[0] of threads 0..49)
  if (t < 50) Strig[0][t] = myTrig[0];

  for (int idx = t; idx < DIM * 32; idx += 512) {
    int i = idx >> 5, c = idx & 31;
    U[i][c] = make_float2((i == c0 + c) ? 1.0f : 0.0f, 0.0f);
  }
  __syncthreads();

  for (int layer = 0; layer < DIM; ++layer) {
    const int start = layer & 1;
    const int npairs = 50 - start;
    // stage NEXT layer's trig into the other buffer (no sync needed before
    // use: this layer's sync covers it; the buffer being written was last
    // read in layer-1, already protected by layer-1's sync).
    if (layer + 1 < DIM) {
      const int nstart = (layer + 1) & 1;
      const int nnp = 50 - nstart;
      const int nbase = ((layer + 1) >> 1) * 99 + nstart * 50;
#pragma unroll
      for (int j = 0; j < 10; ++j) {
        int rel = t + 512 * j - nbase;
        if (rel >= 0 && rel < nnp) Strig[(layer + 1) & 1][rel] = myTrig[j];
      }
    }
    for (int w = t; w < npairs * 32; w += 512) {
      const int p = w >> 5;
      const int c = w & 31;
      const int m = start + 2 * p;
      const int n = m + 1;
      const float4 tg = Strig[layer & 1][p];
      const float cth = tg.x, sth = tg.y, cp = tg.z, sp = tg.w;
      const float2 rm = U[m][c];
      const float2 rn = U[n][c];
      const float ar = cp * rm.x - sp * rm.y;  // (e^{i ph} * rm).re
      const float ai = cp * rm.y + sp * rm.x;  // (e^{i ph} * rm).im
      U[m][c] = make_float2(cth * ar - sth * rn.x, cth * ai - sth * rn.y);
      U[n][c] = make_float2(sth * ar + cth * rn.x, sth * ai + cth * rn.y);
    }
    __syncthreads();
  }

  // epilogue: apply diag phase and pack this block's g_frag tile (kt = blockIdx.x).
  // 3 planes x 7 it-tiles x 64 lanes = 1344 items.
  const int kt = blockIdx.x;
  for (int idx = t; idx < 3 * 7 * 64; idx += 512) {
    int plane = idx / 448;
    int rem = idx - plane * 448;
    int ln = rem & 63;
    int it = rem >> 6;
    int row = it * 16 + (ln & 15);
    int cl = (ln >> 4) * 8;  // local col base within the 32-wide tile
    float cd = 0.f, sd = 0.f;
    if (row < DIM) {
      float d = dphase[row];
      cd = cosf(d);
      sd = sinf(d);
    }
    half8 h;
#pragma unroll
    for (int j = 0; j < 8; ++j) {
      int c = cl + j;
      float v = 0.f;
      if (row < DIM && (c0 + c) < DIM) {
        float2 u = U[row][c];
        float re = cd * u.x - sd * u.y;
        float im = cd * u.y + sd * u.x;
        v = (plane == 0) ? re : ((plane == 1) ? im : -im);
      }
      h[j] = (_Float16)v;
    }
    g_frag[plane][(it * 4 + kt) * 64 + ln] = h;
  }
}

// ---------------------------------------------------------------------------
// Kernel 2: per batch b (one block, 4 waves):
//   Tr = Ur·Xr - Ui·Xi ; Ti = Ui·Xr + Ur·Xi ; out_re = Tr·Ur^T + Ti·Ui^T
// as 16x16x32 f16 MFMAs, M=N=112 (7 tiles), K=256 (two 128-planes).
// Single LDS buffer S = [112][136] f16 (30464 B) serialized through 4 roles:
//   Xr^T -> (stage-1 kt 0..3) -> Xi^T -> (stage-1 kt 4..7)
//   -> A2r = Tr -> (stage-2 kt2 0..3) -> A2i = Ti -> (stage-2 kt2 4..7).
// Occupancy design point: LDS 30.7 KB allows 5 blocks/CU; peak live VGPRs
// ~120 (accR+accI = 112 during stage 1) fits 128 = 4 waves/EU. Pin
// amdgpu_waves_per_eu(4,4): round-1 showed that a bare minimum of 4 lets the
// backend chase 8 waves/EU at 64 VGPRs, spilling 42 floatx4 accumulators to
// scratch (+350 MB of HBM spill traffic, 236 us). Pinning BOTH ends gives
// 4 blocks/CU (50% occ) with zero spills (round 0: this code shape = 120 VGPR).
// Pad invariant: S is zeroed ONCE; X stores only touch [0,100)x[0,104),
// A2 stores only [0,112)x[0,112), so cols [104,128) resp. [112,128) read by
// the MFMA fragments stay zero for the whole kernel (no NaN-from-garbage).
// Wave w owns M-tiles {2w, 2w+1} (tile 7 skipped).
// ---------------------------------------------------------------------------
__global__ __attribute__((amdgpu_waves_per_eu(4, 4)))
__launch_bounds__(256) void transform_kernel(
    const float* __restrict__ xre, const float* __restrict__ xim,
    float* __restrict__ out) {
  __shared__ __align__(16) _Float16 S[15232];  // [112][136] = 30,464 B
  const int tid = threadIdx.x;
  const int wave = tid >> 6;
  const int lane = tid & 63;
  const int quad = lane >> 4;
  const int l16 = lane & 15;
  const int b = blockIdx.x;
  const float* __restrict__ Xre = xre + (size_t)b * (DIM * DIM);
  const float* __restrict__ Xim = xim + (size_t)b * (DIM * DIM);

  // ---- phase 0: zero S once (pad regions rely on staying zero) ----
  {
    int4 z = make_int4(0, 0, 0, 0);
    int4* p = (int4*)S;
    for (int i = tid; i < 15232 * 2 / 16; i += 256) p[i] = z;
  }
  __syncthreads();

  const int m0t = wave * 2;
  floatx4 accR[2][7], accI[2][7];
  const floatx4 zz = {0.f, 0.f, 0.f, 0.f};
#pragma unroll
  for (int a = 0; a < 2; ++a)
#pragma unroll
    for (int n = 0; n < 7; ++n) {
      accR[a][n] = zz;
      accI[a][n] = zz;
    }

  // ---- stage 1, one X plane at a time through S ----
#pragma unroll
  for (int pl = 0; pl < 2; ++pl) {
    const float* __restrict__ Xp = pl ? Xim : Xre;
    // load X^T plane: item g -> (k-octet o, col n). Lane holds fixed n,
    // 8 consecutive k: 8 coalesced dword loads, one b128 LDS write.
    // b128 write 16B-unit stride = 17 -> conflict-free.
    for (int g = tid; g < 1300; g += 256) {
      int o = g / 100;
      int n = g - o * 100;
      int k0 = o * 8;
      half8 h;
#pragma unroll
      for (int j = 0; j < 8; ++j) {
        int k = k0 + j;
        float v = (k < DIM) ? Xp[k * DIM + n] : 0.f;
        h[j] = (_Float16)v;
      }
      *(half8*)&S[n * 136 + k0] = h;
    }
    __syncthreads();

    const half8* __restrict__ frR = pl ? g_frag[2] : g_frag[0];  // [Ur | -Ui]
    const half8* __restrict__ frI = pl ? g_frag[0] : g_frag[1];  // [Ui |  Ur]
#pragma unroll
    for (int ktm = 0; ktm < 4; ++ktm) {
      half8 aR[2], aI[2];
#pragma unroll
      for (int mtl = 0; mtl < 2; ++mtl) {
        int mt = m0t + mtl;
        if (mt < 7) {
          int fi = (mt * 4 + ktm) * 64 + lane;
          aR[mtl] = frR[fi];
          aI[mtl] = frI[fi];
        }
      }
#pragma unroll
      for (int nt = 0; nt < 7; ++nt) {
        half8 bf =
            *(const half8*)&S[(nt * 16 + l16) * 136 + ktm * 32 + quad * 8];
#pragma unroll
        for (int mtl = 0; mtl < 2; ++mtl) {
          if (m0t + mtl < 7) {
            accR[mtl][nt] = __builtin_amdgcn_mfma_f32_16x16x32_f16(
                aR[mtl], bf, accR[mtl][nt], 0, 0, 0);
            accI[mtl][nt] = __builtin_amdgcn_mfma_f32_16x16x32_f16(
                aI[mtl], bf, accI[mtl][nt], 0, 0, 0);
          }
        }
      }
    }
    __syncthreads();  // all reads of this plane done before S is overwritten
  }

  // ---- stage 2, one T half at a time through S ----
  floatx4 acc2[2][7];
#pragma unroll
  for (int a = 0; a < 2; ++a)
#pragma unroll
    for (int n = 0; n < 7; ++n) acc2[a][n] = zz;

#pragma unroll
  for (int h = 0; h < 2; ++h) {
    // write T-half into S as A2[m][n'] (h=0: Tr from accR, h=1: Ti from accI)
#pragma unroll
    for (int mtl = 0; mtl < 2; ++mtl) {
      int mt = m0t + mtl;
      if (mt < 7) {
        int row0 = mt * 16 + quad * 4;
#pragma unroll
        for (int nt = 0; nt < 7; ++nt) {
          int c = nt * 16 + l16;
#pragma unroll
          for (int r = 0; r < 4; ++r) {
            float v = h ? accI[mtl][nt][r] : accR[mtl][nt][r];
            S[(row0 + r) * 136 + c] = (_Float16)v;
          }
        }
      }
    }
    __syncthreads();

    const half8* __restrict__ frB = h ? g_frag[1] : g_frag[0];  // Ur^T / Ui^T
#pragma unroll
    for (int mtl = 0; mtl < 2; ++mtl) {
      int mt = m0t + mtl;
      if (mt >= 7) continue;
      half8 a2f[4];
#pragma unroll
      for (int kt2 = 0; kt2 < 4; ++kt2)
        a2f[kt2] =
            *(const half8*)&S[(mt * 16 + l16) * 136 + kt2 * 32 + quad * 8];
#pragma unroll
      for (int nt = 0; nt < 7; ++nt) {
#pragma unroll
        for (int kt2 = 0; kt2 < 4; ++kt2) {
          acc2[mtl][nt] = __builtin_amdgcn_mfma_f32_16x16x32_f16(
              a2f[kt2], frB[(nt * 4 + kt2) * 64 + lane], acc2[mtl][nt], 0, 0,
              0);
        }
      }
    }
    if (h == 0) __syncthreads();  // stage-2a reads done before Ti overwrites S
  }

  // ---- epilogue: real part only, guarded to 100x100 ----
  float* outb = out + (size_t)b * (DIM * DIM);
#pragma unroll
  for (int mtl = 0; mtl < 2; ++mtl) {
    int mt = m0t + mtl;
    if (mt >= 7) continue;
#pragma unroll
    for (int nt = 0; nt < 7; ++nt) {
      int c = nt * 16 + l16;
      if (c < DIM) {
#pragma unroll
        for (int r = 0; r < 4; ++r) {
          int row = mt * 16 + quad * 4 + r;
          if (row < DIM) outb[row * DIM + c] = acc2[mtl][nt][r];
        }
      }
    }
  }
}

extern "C" void kernel_launch(void* const* d_in, const int* in_sizes, int n_in,
                              void* d_out, int out_size, void* d_ws,
                              size_t ws_size, hipStream_t stream) {
  const float* xre = (const float*)d_in[0];
  const float* xim = (const float*)d_in[1];
  const float* theta = (const float*)d_in[2];
  const float* phi = (const float*)d_in[3];
  const float* dphase = (const float*)d_in[4];
  float* out = (float*)d_out;
  (void)d_ws; (void)ws_size; (void)out_size; (void)n_in;

  hipLaunchKernelGGL(build_U_kernel, dim3(4), dim3(512), 0, stream, theta, phi,
                     dphase);
  const int B = in_sizes[0] / (DIM * DIM);  // 2048
  hipLaunchKernelGGL(transform_kernel, dim3(B), dim3(256), 0, stream, xre, xim,
                     out);
}

// Round 3
// 380.342 us; speedup vs baseline: 1.2886x; 1.2876x over previous
//
#include <hip/hip_runtime.h>

#define DIM 100

typedef _Float16 half8 __attribute__((ext_vector_type(8)));
typedef float floatx4 __attribute__((ext_vector_type(4)));

// Built unitary (after diag phase layer), row-major float2.
__device__ float2 g_U[DIM * DIM];
// MFMA fragment planes: [0]=Ur, [1]=Ui, [2]=-Ui.
// Tile (it,kt) covers U rows [it*16,it*16+16) x cols [kt*32,kt*32+32),
// zero-padded past 100. Element j of lane L in tile (it,kt)
//   = plane[it*16+(L&15)][kt*32+(L>>4)*8+j].
// Serves BOTH stage-1 A-fragments and stage-2 B-fragments.
__device__ half8 g_frag[3][7 * 4 * 64];

// ---------------------------------------------------------------------------
// Kernel 1: build U = D * T_K ... T_1 via a register-resident, barrier-free
// wave scan. One wave per U column (100 waves = 25 blocks x 4 waves).
// Lane l holds rows (2l, 2l+1) of its column as complex f32 registers.
//  - EVEN layers rotate pairs (2l, 2l+1): entirely lane-local, no comm.
//  - ODD layers rotate pairs (2l+1, 2l+2): 4 __shfl + 2 LDS trig reads.
// The previous LDS-column implementation cost ~2.5us/layer in barrier+LDS
// round-trips (~250us total, co-dominant with transform). This scan has ZERO
// barriers in the 100-layer chain. Trig for half the mesh (j=0..24) is
// precomputed into a 39.6KB LDS table (static-LDS 64KB limit forbids the
// full 79.2KB), refilled once at half-time (4 barriers total).
// ---------------------------------------------------------------------------
__global__ __launch_bounds__(256) void build_U_scan(
    const float* __restrict__ theta, const float* __restrict__ phi,
    const float* __restrict__ dphase) {
  __shared__ float4 Strig[2475];  // 25 double-layers x 99 pairs
  const int t = threadIdx.x;
  const int wave = t >> 6;
  const int l = t & 63;
  const int c = blockIdx.x * 4 + wave;  // column 0..99

  // lane l: x0 = row 2l, x1 = row 2l+1 (complex). Lanes >= 50 are dummies.
  float x0r = (2 * l == c) ? 1.f : 0.f, x0i = 0.f;
  float x1r = (2 * l + 1 == c) ? 1.f : 0.f, x1i = 0.f;

  for (int half = 0; half < 2; ++half) {
    __syncthreads();  // half=1: previous reads done before overwrite
    for (int i = t; i < 2475; i += 256) {
      int k = half * 2475 + i;
      float th = theta[k], ph = phi[k];
      Strig[i] = make_float4(cosf(th), sinf(th), cosf(ph), sinf(ph));
    }
    __syncthreads();

    for (int jj = 0; jj < 25; ++jj) {
      const int jb = jj * 99;
      {
        // even layer: pair p = l rotates rows (2l, 2l+1), k = j*99 + p
        float4 tg = Strig[jb + ((l < 50) ? l : 49)];
        float ar = tg.z * x0r - tg.w * x0i;  // (e^{i ph} * rm).re
        float ai = tg.z * x0i + tg.w * x0r;
        float n0r = tg.x * ar - tg.y * x1r;
        float n0i = tg.x * ai - tg.y * x1i;
        float n1r = tg.y * ar + tg.x * x1r;
        float n1i = tg.y * ai + tg.x * x1i;
        x0r = n0r; x0i = n0i; x1r = n1r; x1i = n1i;
      }
      {
        // odd layer: pairs p=0..48 rotate rows (2p+1, 2p+2), k = j*99+50+p.
        // Lane l: its x1 is rm of pair l; its x0 is rn of pair l-1.
        const int ob = jb + 50;
        float4 tg = Strig[ob + ((l < 49) ? l : 48)];        // pair l
        float4 tp = Strig[ob + ((l >= 1) ? (l - 1) : 0)];   // pair l-1
        // shuffle OLD values before overwriting
        float rnr = __shfl_down(x0r, 1);  // x0 of lane l+1 = row 2l+2
        float rni = __shfl_down(x0i, 1);
        float rmr = __shfl_up(x1r, 1);    // x1 of lane l-1 = row 2l-1
        float rmi = __shfl_up(x1i, 1);
        // pair l: new rm (row 2l+1)
        float ar = tg.z * x1r - tg.w * x1i;
        float ai = tg.z * x1i + tg.w * x1r;
        float n1r = tg.x * ar - tg.y * rnr;
        float n1i = tg.x * ai - tg.y * rni;
        // pair l-1: new rn (row 2l)
        float arp = tp.z * rmr - tp.w * rmi;
        float aip = tp.z * rmi + tp.w * rmr;
        float n0r = tp.y * arp + tp.x * x0r;
        float n0i = tp.y * aip + tp.x * x0i;
        if (l <= 48) { x1r = n1r; x1i = n1i; }
        if (l >= 1)  { x0r = n0r; x0i = n0i; }
      }
    }
  }

  // diag phase layer + write out (tiny scatter: 10K float2 stores total)
  if (l < 50 && c < DIM) {
    int r0 = 2 * l, r1 = r0 + 1;
    float d0 = dphase[r0], d1 = dphase[r1];
    float c0 = cosf(d0), s0 = sinf(d0);
    float c1 = cosf(d1), s1 = sinf(d1);
    g_U[r0 * DIM + c] = make_float2(c0 * x0r - s0 * x0i, c0 * x0i + s0 * x0r);
    g_U[r1 * DIM + c] = make_float2(c1 * x1r - s1 * x1i, c1 * x1i + s1 * x1r);
  }
}

// ---------------------------------------------------------------------------
// Kernel 2: pack U into f16 MFMA fragment planes (Ur, Ui, -Ui), zero-padded.
// Grid-parallel: 21 blocks x 256 threads = 5376 = 3*1792 items, one each.
// ---------------------------------------------------------------------------
__global__ __launch_bounds__(256) void pack_kernel() {
  const int g = blockIdx.x * 256 + threadIdx.x;  // < 5376 by construction
  int plane = g / 1792;
  int rem = g - plane * 1792;
  int lane = rem & 63;
  int tile = rem >> 6;
  int it = tile >> 2, kt = tile & 3;
  int row = it * 16 + (lane & 15);
  int col0 = kt * 32 + (lane >> 4) * 8;
  half8 h;
#pragma unroll
  for (int j = 0; j < 8; ++j) {
    int col = col0 + j;
    float v = 0.f;
    if (row < DIM && col < DIM) {
      float2 u = g_U[row * DIM + col];
      v = (plane == 0) ? u.x : ((plane == 1) ? u.y : -u.y);
    }
    h[j] = (_Float16)v;
  }
  g_frag[plane][rem] = h;
}

// ---------------------------------------------------------------------------
// Kernel 3: per batch b (one block, 4 waves):
//   Tr = Ur·Xr - Ui·Xi ; Ti = Ui·Xr + Ur·Xi ; out_re = Tr·Ur^T + Ti·Ui^T
// as 16x16x32 f16 MFMAs, M=N=112 (7 tiles), K=256 (two 128-planes).
// Single LDS buffer S (used region [112][136] = 30464B) serialized through:
//   Xr^T -> (stage-1 kt 0..3) -> Xi^T -> (stage-1 kt 4..7)
//   -> A2r = Tr -> (stage-2 kt2 0..3) -> A2i = Ti -> (stage-2 kt2 4..7).
// OCCUPANCY/VGPR DESIGN (hard-won, rounds 0-2): the backend's VGPR budget =
// 512/target-waves-per-EU on a coarse {64,128,256} granule, where the target
// comes from LDS-limited occupancy. waves_per_eu attributes are IGNORED.
//   60928B LDS -> 2 blk/CU -> 2 w/EU -> 256-reg budget -> 120 used (r0, 152us)
//   30720B LDS -> 5 blk/CU -> 5 w/EU -> rounds UP to 8 w/EU -> 64 regs ->
//                 42 vec4 accs spilled, +180MB scratch writes (r1/r2, 236us)
// Fix: PAD S to 33280B so blocks/CU = 4 exactly -> 4 w/EU -> 128-reg budget
// -> ~120-reg kernel fits spill-free at 50% occupancy. Do not shrink S below
// 32769B and do not add waves_per_eu/launch_bounds minima.
// Pad invariant: S is zeroed ONCE; X stores touch [0,100)x[0,104) only,
// A2 stores [0,112)x[0,112) only, so cols [104,128)/[112,128) read by MFMA
// fragments stay zero all kernel. Wave w owns M-tiles {2w, 2w+1} (7 skipped).
// ---------------------------------------------------------------------------
__global__ __launch_bounds__(256) void transform_kernel(
    const float* __restrict__ xre, const float* __restrict__ xim,
    float* __restrict__ out) {
  __shared__ __align__(16) _Float16 S[16640];  // 33280 B; only [0,15232) used
  const int tid = threadIdx.x;
  const int wave = tid >> 6;
  const int lane = tid & 63;
  const int quad = lane >> 4;
  const int l16 = lane & 15;
  const int b = blockIdx.x;
  const float* __restrict__ Xre = xre + (size_t)b * (DIM * DIM);
  const float* __restrict__ Xim = xim + (size_t)b * (DIM * DIM);

  // ---- phase 0: zero used region once (pad regions rely on staying zero) ----
  {
    int4 z = make_int4(0, 0, 0, 0);
    int4* p = (int4*)S;
    for (int i = tid; i < 15232 * 2 / 16; i += 256) p[i] = z;
  }
  __syncthreads();

  const int m0t = wave * 2;
  floatx4 accR[2][7], accI[2][7];
  const floatx4 zz = {0.f, 0.f, 0.f, 0.f};
#pragma unroll
  for (int a = 0; a < 2; ++a)
#pragma unroll
    for (int n = 0; n < 7; ++n) {
      accR[a][n] = zz;
      accI[a][n] = zz;
    }

  // ---- stage 1, one X plane at a time through S ----
#pragma unroll
  for (int pl = 0; pl < 2; ++pl) {
    const float* __restrict__ Xp = pl ? Xim : Xre;
    // load X^T plane: item g -> (k-octet o, col n). Lane holds fixed n,
    // 8 consecutive k: 8 coalesced dword loads, one b128 LDS write.
    for (int g = tid; g < 1300; g += 256) {
      int o = g / 100;
      int n = g - o * 100;
      int k0 = o * 8;
      half8 h;
#pragma unroll
      for (int j = 0; j < 8; ++j) {
        int k = k0 + j;
        float v = (k < DIM) ? Xp[k * DIM + n] : 0.f;
        h[j] = (_Float16)v;
      }
      *(half8*)&S[n * 136 + k0] = h;
    }
    __syncthreads();

    const half8* __restrict__ frR = pl ? g_frag[2] : g_frag[0];  // [Ur | -Ui]
    const half8* __restrict__ frI = pl ? g_frag[0] : g_frag[1];  // [Ui |  Ur]
#pragma unroll
    for (int ktm = 0; ktm < 4; ++ktm) {
      half8 aR[2], aI[2];
#pragma unroll
      for (int mtl = 0; mtl < 2; ++mtl) {
        int mt = m0t + mtl;
        if (mt < 7) {
          int fi = (mt * 4 + ktm) * 64 + lane;
          aR[mtl] = frR[fi];
          aI[mtl] = frI[fi];
        }
      }
#pragma unroll
      for (int nt = 0; nt < 7; ++nt) {
        half8 bf =
            *(const half8*)&S[(nt * 16 + l16) * 136 + ktm * 32 + quad * 8];
#pragma unroll
        for (int mtl = 0; mtl < 2; ++mtl) {
          if (m0t + mtl < 7) {
            accR[mtl][nt] = __builtin_amdgcn_mfma_f32_16x16x32_f16(
                aR[mtl], bf, accR[mtl][nt], 0, 0, 0);
            accI[mtl][nt] = __builtin_amdgcn_mfma_f32_16x16x32_f16(
                aI[mtl], bf, accI[mtl][nt], 0, 0, 0);
          }
        }
      }
    }
    __syncthreads();  // all reads of this plane done before S is overwritten
  }

  // ---- stage 2, one T half at a time through S ----
  floatx4 acc2[2][7];
#pragma unroll
  for (int a = 0; a < 2; ++a)
#pragma unroll
    for (int n = 0; n < 7; ++n) acc2[a][n] = zz;

#pragma unroll
  for (int h = 0; h < 2; ++h) {
    // write T-half into S as A2[m][n'] (h=0: Tr from accR, h=1: Ti from accI)
#pragma unroll
    for (int mtl = 0; mtl < 2; ++mtl) {
      int mt = m0t + mtl;
      if (mt < 7) {
        int row0 = mt * 16 + quad * 4;
#pragma unroll
        for (int nt = 0; nt < 7; ++nt) {
          int c = nt * 16 + l16;
#pragma unroll
          for (int r = 0; r < 4; ++r) {
            float v = h ? accI[mtl][nt][r] : accR[mtl][nt][r];
            S[(row0 + r) * 136 + c] = (_Float16)v;
          }
        }
      }
    }
    __syncthreads();

    const half8* __restrict__ frB = h ? g_frag[1] : g_frag[0];  // Ur^T / Ui^T
#pragma unroll
    for (int mtl = 0; mtl < 2; ++mtl) {
      int mt = m0t + mtl;
      if (mt >= 7) continue;
      half8 a2f[4];
#pragma unroll
      for (int kt2 = 0; kt2 < 4; ++kt2)
        a2f[kt2] =
            *(const half8*)&S[(mt * 16 + l16) * 136 + kt2 * 32 + quad * 8];
#pragma unroll
      for (int nt = 0; nt < 7; ++nt) {
#pragma unroll
        for (int kt2 = 0; kt2 < 4; ++kt2) {
          acc2[mtl][nt] = __builtin_amdgcn_mfma_f32_16x16x32_f16(
              a2f[kt2], frB[(nt * 4 + kt2) * 64 + lane], acc2[mtl][nt], 0, 0,
              0);
        }
      }
    }
    if (h == 0) __syncthreads();  // stage-2a reads done before Ti overwrites S
  }

  // ---- epilogue: real part only, guarded to 100x100 ----
  float* outb = out + (size_t)b * (DIM * DIM);
#pragma unroll
  for (int mtl = 0; mtl < 2; ++mtl) {
    int mt = m0t + mtl;
    if (mt >= 7) continue;
#pragma unroll
    for (int nt = 0; nt < 7; ++nt) {
      int c = nt * 16 + l16;
      if (c < DIM) {
#pragma unroll
        for (int r = 0; r < 4; ++r) {
          int row = mt * 16 + quad * 4 + r;
          if (row < DIM) outb[row * DIM + c] = acc2[mtl][nt][r];
        }
      }
    }
  }
}

extern "C" void kernel_launch(void* const* d_in, const int* in_sizes, int n_in,
                              void* d_out, int out_size, void* d_ws,
                              size_t ws_size, hipStream_t stream) {
  const float* xre = (const float*)d_in[0];
  const float* xim = (const float*)d_in[1];
  const float* theta = (const float*)d_in[2];
  const float* phi = (const float*)d_in[3];
  const float* dphase = (const float*)d_in[4];
  float* out = (float*)d_out;
  (void)d_ws; (void)ws_size; (void)out_size; (void)n_in;

  hipLaunchKernelGGL(build_U_scan, dim3(25), dim3(256), 0, stream, theta, phi,
                     dphase);
  hipLaunchKernelGGL(pack_kernel, dim3(21), dim3(256), 0, stream);
  const int B = in_sizes[0] / (DIM * DIM);  // 2048
  hipLaunchKernelGGL(transform_kernel, dim3(B), dim3(256), 0, stream, xre, xim,
                     out);
}

// Round 4
// 341.246 us; speedup vs baseline: 1.4362x; 1.1146x over previous
//
#include <hip/hip_runtime.h>

#define DIM 100

typedef _Float16 half8 __attribute__((ext_vector_type(8)));
typedef float floatx4 __attribute__((ext_vector_type(4)));

// Built unitary (after diag phase layer), row-major float2.
__device__ float2 g_U[DIM * DIM];
// MFMA fragment planes: [0]=Ur, [1]=Ui, [2]=-Ui.
// Tile (it,kt) covers U rows [it*16,it*16+16) x cols [kt*32,kt*32+32),
// zero-padded past 100. Element j of lane L in tile (it,kt)
//   = plane[it*16+(L&15)][kt*32+(L>>4)*8+j].
// Serves BOTH stage-1 A-fragments and stage-2 B-fragments.
__device__ half8 g_frag[3][7 * 4 * 64];

// ---------------------------------------------------------------------------
// Kernel 1: build U = D * T_K ... T_1 via a register-resident, barrier-free
// wave scan. One wave per U column (100 waves = 25 blocks x 4 waves).
// Lane l holds rows (2l, 2l+1) of its column as complex f32 registers.
//  - EVEN layers rotate pairs (2l, 2l+1): entirely lane-local, no comm.
//  - ODD layers rotate pairs (2l+1, 2l+2): 4 __shfl + 2 LDS trig reads.
// Zero barriers inside the 100-layer chain; trig for half the mesh staged in
// a 39.6KB LDS table, refilled once (4 barriers total).
// ---------------------------------------------------------------------------
__global__ __launch_bounds__(256) void build_U_scan(
    const float* __restrict__ theta, const float* __restrict__ phi,
    const float* __restrict__ dphase) {
  __shared__ float4 Strig[2475];  // 25 double-layers x 99 pairs
  const int t = threadIdx.x;
  const int wave = t >> 6;
  const int l = t & 63;
  const int c = blockIdx.x * 4 + wave;  // column 0..99

  // lane l: x0 = row 2l, x1 = row 2l+1 (complex). Lanes >= 50 are dummies.
  float x0r = (2 * l == c) ? 1.f : 0.f, x0i = 0.f;
  float x1r = (2 * l + 1 == c) ? 1.f : 0.f, x1i = 0.f;

  for (int half = 0; half < 2; ++half) {
    __syncthreads();  // half=1: previous reads done before overwrite
    for (int i = t; i < 2475; i += 256) {
      int k = half * 2475 + i;
      float th = theta[k], ph = phi[k];
      Strig[i] = make_float4(cosf(th), sinf(th), cosf(ph), sinf(ph));
    }
    __syncthreads();

    for (int jj = 0; jj < 25; ++jj) {
      const int jb = jj * 99;
      {
        // even layer: pair p = l rotates rows (2l, 2l+1), k = j*99 + p
        float4 tg = Strig[jb + ((l < 50) ? l : 49)];
        float ar = tg.z * x0r - tg.w * x0i;  // (e^{i ph} * rm).re
        float ai = tg.z * x0i + tg.w * x0r;
        float n0r = tg.x * ar - tg.y * x1r;
        float n0i = tg.x * ai - tg.y * x1i;
        float n1r = tg.y * ar + tg.x * x1r;
        float n1i = tg.y * ai + tg.x * x1i;
        x0r = n0r; x0i = n0i; x1r = n1r; x1i = n1i;
      }
      {
        // odd layer: pairs p=0..48 rotate rows (2p+1, 2p+2), k = j*99+50+p.
        // Lane l: its x1 is rm of pair l; its x0 is rn of pair l-1.
        const int ob = jb + 50;
        float4 tg = Strig[ob + ((l < 49) ? l : 48)];        // pair l
        float4 tp = Strig[ob + ((l >= 1) ? (l - 1) : 0)];   // pair l-1
        // shuffle OLD values before overwriting
        float rnr = __shfl_down(x0r, 1);  // x0 of lane l+1 = row 2l+2
        float rni = __shfl_down(x0i, 1);
        float rmr = __shfl_up(x1r, 1);    // x1 of lane l-1 = row 2l-1
        float rmi = __shfl_up(x1i, 1);
        // pair l: new rm (row 2l+1)
        float ar = tg.z * x1r - tg.w * x1i;
        float ai = tg.z * x1i + tg.w * x1r;
        float n1r = tg.x * ar - tg.y * rnr;
        float n1i = tg.x * ai - tg.y * rni;
        // pair l-1: new rn (row 2l)
        float arp = tp.z * rmr - tp.w * rmi;
        float aip = tp.z * rmi + tp.w * rmr;
        float n0r = tp.y * arp + tp.x * x0r;
        float n0i = tp.y * aip + tp.x * x0i;
        if (l <= 48) { x1r = n1r; x1i = n1i; }
        if (l >= 1)  { x0r = n0r; x0i = n0i; }
      }
    }
  }

  // diag phase layer + write out (tiny scatter: 10K float2 stores total)
  if (l < 50 && c < DIM) {
    int r0 = 2 * l, r1 = r0 + 1;
    float d0 = dphase[r0], d1 = dphase[r1];
    float c0 = cosf(d0), s0 = sinf(d0);
    float c1 = cosf(d1), s1 = sinf(d1);
    g_U[r0 * DIM + c] = make_float2(c0 * x0r - s0 * x0i, c0 * x0i + s0 * x0r);
    g_U[r1 * DIM + c] = make_float2(c1 * x1r - s1 * x1i, c1 * x1i + s1 * x1r);
  }
}

// ---------------------------------------------------------------------------
// Kernel 2: pack U into f16 MFMA fragment planes (Ur, Ui, -Ui), zero-padded.
// Grid-parallel: 21 blocks x 256 threads = 5376 = 3*1792 items, one each.
// ---------------------------------------------------------------------------
__global__ __launch_bounds__(256) void pack_kernel() {
  const int g = blockIdx.x * 256 + threadIdx.x;  // < 5376 by construction
  int plane = g / 1792;
  int rem = g - plane * 1792;
  int lane = rem & 63;
  int tile = rem >> 6;
  int it = tile >> 2, kt = tile & 3;
  int row = it * 16 + (lane & 15);
  int col0 = kt * 32 + (lane >> 4) * 8;
  half8 h;
#pragma unroll
  for (int j = 0; j < 8; ++j) {
    int col = col0 + j;
    float v = 0.f;
    if (row < DIM && col < DIM) {
      float2 u = g_U[row * DIM + col];
      v = (plane == 0) ? u.x : ((plane == 1) ? u.y : -u.y);
    }
    h[j] = (_Float16)v;
  }
  g_frag[plane][rem] = h;
}

// ---------------------------------------------------------------------------
// Kernel 3: per batch b, ONE block of 8 waves (512 thr), wave w owns M-tile w
// (w = 7 stages only):
//   Tr = Ur·Xr - Ui·Xi ; Ti = Ui·Xr + Ur·Xi ; out_re = Tr·Ur^T + Ti·Ui^T
// as 16x16x32 f16 MFMAs, M=N=112 (7 tiles), K=256 (two 128-planes).
//
// REGISTER/OCCUPANCY MODEL (rounds 0-3, hard-won): occupancy granularity is
// total (VGPR+AGPR) regs rounded to {64,128,256}; waves/CU = 2048/total.
// rocprof VGPR_Count EXCLUDES AGPRs.
//   r0/r3: 4 waves x 2 M-tiles -> 28 acc-vec4 live -> total ~256 -> 8 waves/CU
//          (22% occ) regardless of LDS. LDS padding (r3) was useless; extra
//          barriers made it slower (223us vs 152us).
//   r1/r2: compiler chased 128-total with 28 live vec4 -> spilled -> +180MB.
// THIS kernel: 1 M-tile/wave -> 14 acc-vec4 live, peak ~90 regs -> total 128
// -> 16 waves/CU (50%). LDS 60928B -> 2 blocks/CU x 8 waves = same 16 waves,
// so the compiler's LDS-derived budget (4 waves/EU -> 128 regs) is exactly
// achievable: no spill-chasing, no 256-rounding. Low-barrier phase plan
// (4 syncs): both X planes staged at once; A2 = [Tr|Ti] written once.
//
// Pad invariants: S zeroed once; X^T writes touch [n<100][k<104] only; A2
// K-pad stripes [112,128)u[240,256) re-zeroed before stage-2; rows 0..111 of
// A2 all written (7 waves x 16 rows).
// ---------------------------------------------------------------------------
__global__ __launch_bounds__(512) void transform_kernel(
    const float* __restrict__ xre, const float* __restrict__ xim,
    float* __restrict__ out) {
  // phase 1: X^T planes [2][112][136] f16; phase 3: A2 [112][264] f16.
  __shared__ __align__(16) _Float16 S[30464];  // 60,928 B
  const int tid = threadIdx.x;
  const int wave = tid >> 6;
  const int lane = tid & 63;
  const int quad = lane >> 4;
  const int l16 = lane & 15;
  const int mt = wave;  // M-tile of this wave (7 = staging-only wave)
  const int b = blockIdx.x;
  const float* __restrict__ Xre = xre + (size_t)b * (DIM * DIM);
  const float* __restrict__ Xim = xim + (size_t)b * (DIM * DIM);

  // ---- phase 0: zero S once (pad regions rely on staying zero) ----
  {
    int4 z = make_int4(0, 0, 0, 0);
    int4* p = (int4*)S;
    for (int i = tid; i < 30464 * 2 / 16; i += 512) p[i] = z;
  }
  __syncthreads();

  // ---- phase 1: stage BOTH X planes as X^T f16: S[pl*15232 + n*136 + k].
  // Item g -> (plane pl, k-octet o, col n): 8 coalesced dword loads -> one
  // b128 LDS write (16B-aligned: 136 halfs = 272 B = 17*16; 2-way bank
  // aliasing only = free).
  for (int g = tid; g < 2600; g += 512) {
    int pl = g / 1300;
    int r = g - pl * 1300;
    int o = r / 100;
    int n = r - o * 100;
    const float* __restrict__ Xp = pl ? Xim : Xre;
    int k0 = o * 8;
    half8 h;
#pragma unroll
    for (int j = 0; j < 8; ++j) {
      int k = k0 + j;
      float v = (k < DIM) ? Xp[k * DIM + n] : 0.f;
      h[j] = (_Float16)v;
    }
    *(half8*)&S[pl * 15232 + n * 136 + k0] = h;
  }
  __syncthreads();

  // ---- phase 2: stage-1 MFMAs, accumulators in registers ----
  floatx4 accR[7], accI[7];
  const floatx4 zz = {0.f, 0.f, 0.f, 0.f};
#pragma unroll
  for (int n = 0; n < 7; ++n) {
    accR[n] = zz;
    accI[n] = zz;
  }
  if (mt < 7) {
    for (int kt = 0; kt < 8; ++kt) {
      const int ktm = kt & 3;
      const half8* __restrict__ frR = (kt < 4) ? g_frag[0] : g_frag[2];
      const half8* __restrict__ frI = (kt < 4) ? g_frag[1] : g_frag[0];
      const int fi = (mt * 4 + ktm) * 64 + lane;
      half8 aR = frR[fi];  // [Ur | -Ui]
      half8 aI = frI[fi];  // [Ui |  Ur]
      const int pb = (kt >> 2) * 15232;
#pragma unroll
      for (int nt = 0; nt < 7; ++nt) {
        half8 bf =
            *(const half8*)&S[pb + (nt * 16 + l16) * 136 + ktm * 32 + quad * 8];
        accR[nt] = __builtin_amdgcn_mfma_f32_16x16x32_f16(aR, bf, accR[nt], 0,
                                                          0, 0);
        accI[nt] = __builtin_amdgcn_mfma_f32_16x16x32_f16(aI, bf, accI[nt], 0,
                                                          0, 0);
      }
    }
  }
  __syncthreads();  // all X^T reads complete before S is overwritten

  // ---- phase 3: store T into S as A2[m][k'] (stride 264), [Tr | Ti]. ----
  // K-pad stripes k' in [112,128) u [240,256) must be zero.
  {
    int2 z2 = make_int2(0, 0);
    for (int g = tid; g < 896; g += 512) {
      int m = g >> 3;
      int rest = g & 7;
      int base = (rest & 4) ? 240 : 112;
      int off = (rest & 3) * 4;
      *(int2*)&S[m * 264 + base + off] = z2;
    }
  }
  if (mt < 7) {
    int row0 = mt * 16 + quad * 4;
#pragma unroll
    for (int nt = 0; nt < 7; ++nt) {
      int c = nt * 16 + l16;
#pragma unroll
      for (int r = 0; r < 4; ++r) {
        S[(row0 + r) * 264 + c] = (_Float16)accR[nt][r];
        S[(row0 + r) * 264 + 128 + c] = (_Float16)accI[nt][r];
      }
    }
  }
  __syncthreads();

  // ---- phase 4: stage-2 out_re = [Tr|Ti] · [Ur^T; Ui^T] ----
  floatx4 acc2[7];
#pragma unroll
  for (int n = 0; n < 7; ++n) acc2[n] = zz;
  if (mt < 7) {
    half8 a2[8];
#pragma unroll
    for (int kt2 = 0; kt2 < 8; ++kt2)
      a2[kt2] = *(const half8*)&S[(mt * 16 + l16) * 264 + kt2 * 32 + quad * 8];
#pragma unroll
    for (int nt = 0; nt < 7; ++nt) {
#pragma unroll
      for (int kt2 = 0; kt2 < 8; ++kt2) {
        const half8* __restrict__ frB = (kt2 < 4) ? g_frag[0] : g_frag[1];
        half8 bf = frB[(nt * 4 + (kt2 & 3)) * 64 + lane];
        acc2[nt] = __builtin_amdgcn_mfma_f32_16x16x32_f16(a2[kt2], bf, acc2[nt],
                                                          0, 0, 0);
      }
    }
  }

  // ---- epilogue: real part only, guarded to 100x100 ----
  if (mt < 7) {
    float* outb = out + (size_t)b * (DIM * DIM);
#pragma unroll
    for (int nt = 0; nt < 7; ++nt) {
      int c = nt * 16 + l16;
      if (c < DIM) {
#pragma unroll
        for (int r = 0; r < 4; ++r) {
          int row = mt * 16 + quad * 4 + r;
          if (row < DIM) outb[row * DIM + c] = acc2[nt][r];
        }
      }
    }
  }
}

extern "C" void kernel_launch(void* const* d_in, const int* in_sizes, int n_in,
                              void* d_out, int out_size, void* d_ws,
                              size_t ws_size, hipStream_t stream) {
  const float* xre = (const float*)d_in[0];
  const float* xim = (const float*)d_in[1];
  const float* theta = (const float*)d_in[2];
  const float* phi = (const float*)d_in[3];
  const float* dphase = (const float*)d_in[4];
  float* out = (float*)d_out;
  (void)d_ws; (void)ws_size; (void)out_size; (void)n_in;

  hipLaunchKernelGGL(build_U_scan, dim3(25), dim3(256), 0, stream, theta, phi,
                     dphase);
  hipLaunchKernelGGL(pack_kernel, dim3(21), dim3(256), 0, stream);
  const int B = in_sizes[0] / (DIM * DIM);  // 2048
  hipLaunchKernelGGL(transform_kernel, dim3(B), dim3(512), 0, stream, xre, xim,
                     out);
}

// Round 5
// 310.024 us; speedup vs baseline: 1.5809x; 1.1007x over previous
//
#include <hip/hip_runtime.h>

#define DIM 100

typedef _Float16 half8 __attribute__((ext_vector_type(8)));
typedef float floatx4 __attribute__((ext_vector_type(4)));
typedef unsigned int uint4v __attribute__((ext_vector_type(4)));

// Built unitary (after diag phase layer), row-major float2.
__device__ float2 g_U[DIM * DIM];
// MFMA fragment planes: [0]=Ur, [1]=Ui  (-Ui is derived in-kernel by sign
// flip). Tile (it,kt) covers U rows [it*16,it*16+16) x cols [kt*32,kt*32+32),
// zero-padded past 100. Element j of lane L of tile (it,kt)
//   = plane[it*16+(L&15)][kt*32+(L>>4)*8+j].
// A-frag(U) == B-frag(U^T) for 16x16x32, so one layout serves both stages.
__device__ half8 g_frag[2][7 * 4 * 64];

__device__ __forceinline__ half8 neg_h8(half8 v) {
  uint4v u;
  __builtin_memcpy(&u, &v, 16);
  u ^= 0x80008000u;  // flip f16 sign bits (exact negation)
  half8 r;
  __builtin_memcpy(&r, &u, 16);
  return r;
}

// ---------------------------------------------------------------------------
// Kernel 1: build U = D * T_K ... T_1 via a register-resident, barrier-free
// wave scan. One wave per U column (100 waves = 25 blocks x 4 waves).
// Lane l holds rows (2l, 2l+1) of its column as complex f32 registers.
//  - EVEN layers rotate pairs (2l, 2l+1): lane-local.
//  - ODD layers rotate pairs (2l+1, 2l+2): 4 __shfl.
// Trig for the NEXT double-layer is prefetched into registers while the
// current one computes, so the 120-cycle LDS latency is off the serial chain.
// ---------------------------------------------------------------------------
__global__ __launch_bounds__(256) void build_U_scan(
    const float* __restrict__ theta, const float* __restrict__ phi,
    const float* __restrict__ dphase) {
  __shared__ float4 Strig[2475];  // 25 double-layers x 99 pairs
  const int t = threadIdx.x;
  const int wave = t >> 6;
  const int l = t & 63;
  const int c = blockIdx.x * 4 + wave;  // column 0..99

  // lane l: x0 = row 2l, x1 = row 2l+1 (complex). Lanes >= 50 are dummies.
  float x0r = (2 * l == c) ? 1.f : 0.f, x0i = 0.f;
  float x1r = (2 * l + 1 == c) ? 1.f : 0.f, x1i = 0.f;

  const int eIdx = (l < 50) ? l : 49;             // even-layer pair index
  const int oIdx = 50 + ((l < 49) ? l : 48);      // odd-layer pair l
  const int pIdx = 50 + ((l >= 1) ? (l - 1) : 0); // odd-layer pair l-1

  for (int half = 0; half < 2; ++half) {
    __syncthreads();  // half=1: previous reads done before overwrite
    for (int i = t; i < 2475; i += 256) {
      int k = half * 2475 + i;
      float th = theta[k], ph = phi[k];
      Strig[i] = make_float4(cosf(th), sinf(th), cosf(ph), sinf(ph));
    }
    __syncthreads();

    float4 tgE = Strig[eIdx];
    float4 tgO = Strig[oIdx];
    float4 tpO = Strig[pIdx];
    for (int jj = 0; jj < 25; ++jj) {
      float4 nE = tgE, nO = tgO, nP = tpO;
      if (jj < 24) {  // prefetch next double-layer's trig
        int nb = (jj + 1) * 99;
        nE = Strig[nb + eIdx];
        nO = Strig[nb + oIdx];
        nP = Strig[nb + pIdx];
      }
      {
        // even layer: pair p = l rotates rows (2l, 2l+1)
        float ar = tgE.z * x0r - tgE.w * x0i;  // (e^{i ph} * rm).re
        float ai = tgE.z * x0i + tgE.w * x0r;
        float n0r = tgE.x * ar - tgE.y * x1r;
        float n0i = tgE.x * ai - tgE.y * x1i;
        float n1r = tgE.y * ar + tgE.x * x1r;
        float n1i = tgE.y * ai + tgE.x * x1i;
        x0r = n0r; x0i = n0i; x1r = n1r; x1i = n1i;
      }
      {
        // odd layer: pairs p=0..48 rotate rows (2p+1, 2p+2).
        // Lane l: its x1 is rm of pair l; its x0 is rn of pair l-1.
        float rnr = __shfl_down(x0r, 1);  // row 2l+2
        float rni = __shfl_down(x0i, 1);
        float rmr = __shfl_up(x1r, 1);    // row 2l-1
        float rmi = __shfl_up(x1i, 1);
        float ar = tgO.z * x1r - tgO.w * x1i;
        float ai = tgO.z * x1i + tgO.w * x1r;
        float n1r = tgO.x * ar - tgO.y * rnr;
        float n1i = tgO.x * ai - tgO.y * rni;
        float arp = tpO.z * rmr - tpO.w * rmi;
        float aip = tpO.z * rmi + tpO.w * rmr;
        float n0r = tpO.y * arp + tpO.x * x0r;
        float n0i = tpO.y * aip + tpO.x * x0i;
        if (l <= 48) { x1r = n1r; x1i = n1i; }
        if (l >= 1)  { x0r = n0r; x0i = n0i; }
      }
      tgE = nE; tgO = nO; tpO = nP;
    }
  }

  // diag phase layer + write out
  if (l < 50 && c < DIM) {
    int r0 = 2 * l, r1 = r0 + 1;
    float d0 = dphase[r0], d1 = dphase[r1];
    float c0 = cosf(d0), s0 = sinf(d0);
    float c1 = cosf(d1), s1 = sinf(d1);
    g_U[r0 * DIM + c] = make_float2(c0 * x0r - s0 * x0i, c0 * x0i + s0 * x0r);
    g_U[r1 * DIM + c] = make_float2(c1 * x1r - s1 * x1i, c1 * x1i + s1 * x1r);
  }
}

// ---------------------------------------------------------------------------
// Kernel 2: pack U into f16 MFMA fragment planes (Ur, Ui), zero-padded.
// 14 blocks x 256 threads = 3584 = 2*1792 items, one each.
// ---------------------------------------------------------------------------
__global__ __launch_bounds__(256) void pack_kernel() {
  const int g = blockIdx.x * 256 + threadIdx.x;  // < 3584 by construction
  int plane = g / 1792;
  int rem = g - plane * 1792;
  int lane = rem & 63;
  int tile = rem >> 6;
  int it = tile >> 2, kt = tile & 3;
  int row = it * 16 + (lane & 15);
  int col0 = kt * 32 + (lane >> 4) * 8;
  half8 h;
#pragma unroll
  for (int j = 0; j < 8; ++j) {
    int col = col0 + j;
    float v = 0.f;
    if (row < DIM && col < DIM) {
      float2 u = g_U[row * DIM + col];
      v = (plane == 0) ? u.x : u.y;
    }
    h[j] = (_Float16)v;
  }
  g_frag[plane][rem] = h;
}

// ---------------------------------------------------------------------------
// Kernel 3: per batch b, ONE block of 8 waves (512 thr), wave w owns M-tile w
// (w=7 stages only):
//   Tr = Ur·Xr - Ui·Xi ; Ti = Ui·Xr + Ur·Xi ; out_re = Tr·Ur^T + Ti·Ui^T
// as 16x16x32 f16 MFMAs, M=N=112 (7 tiles), K=256.
//
// ROUND-4 DIAGNOSIS: at 43% occupancy everything still idled (MfmaUtil 8.6%)
// because every wave re-streamed U fragments from GLOBAL memory on the MFMA
// critical path (phase-4 alone: 57 KB/wave; ~4 MB L2 traffic per CU per
// kernel), thrashing L1 and exposing ~200-cycle L2 latency per fragment.
// THIS kernel caches both U fragment planes in LDS ONCE per block (57,344 B,
// 7 b128 loads/thread) and derives -Ui by f16 sign-flip (VALU was 88% idle).
// Two ping-pong X/A2 buffers let Xr/Xi (then A2r/A2i) coexist -> 4 barriers
// total and a stage-2 that is pure LDS + MFMA.
//
// LDS = 57,344 (UF) + 2 x 30,464 (XA0/XA1) = 118,272 B, DYNAMIC (static
// limit is 64 KB; gfx950 supports up to 160 KB/WG -- HK/AITER kernels use
// 128-160 KB). 1 block/CU x 8 waves = 25% occupancy -- acceptable because
// all compute-path operands are now LDS-local.
// REGISTER MODEL (r0-r3): occupancy granule = total(VGPR+AGPR) in {64,128,
// 256}; with dynamic LDS the backend cannot derive a blocks/CU target, so
// __launch_bounds__(512,2) pins min 2 waves/EU -> 256-reg budget -> ~115
// live regs fit spill-free. Do NOT re-add static LDS or tighter bounds.
//
// Pad invariants: XA pad zones (rows 100..111 all cols; cols 104..135 of
// rows 0..99) are zeroed ONCE, disjoint from X writes (rows<100, cols<104)
// and A2 writes (rows<112, cols<112; rows/cols 100..111 carry exact zeros
// from the zero-padded U fragments). Xi global loads are ISSUED before the
// stage-1a MFMA loop so HBM latency hides under compute (T14).
// ---------------------------------------------------------------------------
__global__ __launch_bounds__(512, 2) void transform_kernel(
    const float* __restrict__ xre, const float* __restrict__ xim,
    float* __restrict__ out) {
  extern __shared__ __align__(16) _Float16 S[];  // 118,272 B dynamic
  half8* __restrict__ UF = (half8*)S;       // UF[pl*1792 + tile*64 + lane]
  _Float16* __restrict__ XA0 = S + 28672;   // [112][136] f16
  _Float16* __restrict__ XA1 = S + 43904;   // [112][136] f16

  const int tid = threadIdx.x;
  const int wave = tid >> 6;
  const int lane = tid & 63;
  const int quad = lane >> 4;
  const int l16 = lane & 15;
  const int mt = wave;  // M-tile of this wave (7 = staging-only)
  const int b = blockIdx.x;
  const float* __restrict__ Xre = xre + (size_t)b * (DIM * DIM);
  const float* __restrict__ Xim = xim + (size_t)b * (DIM * DIM);

  // ---- P0: issue U-fill + Xr loads; zero pad zones; write LDS ----
  const half8* __restrict__ gfr = &g_frag[0][0];  // planes 0,1 contiguous
  half8 uf[7];
#pragma unroll
  for (int j = 0; j < 7; ++j) uf[j] = gfr[tid + 512 * j];  // 3584 exact

  float xr[3][8];
#pragma unroll
  for (int it = 0; it < 3; ++it) {
    int g = tid + 512 * it;
    if (g < 1300) {
      int o = g / 100, n = g - o * 100, k0 = o * 8;
#pragma unroll
      for (int j = 0; j < 8; ++j) {
        int k = k0 + j;
        xr[it][j] = (k < DIM) ? Xre[k * DIM + n] : 0.f;
      }
    }
  }

  // zero pad zones of BOTH buffers (disjoint from all data writes):
  // zone1: rows 100..111 full (12*17 int4 per buf); zone2: int4 cols 13..16
  // of rows 0..99 (100*4 per buf). 2*(204+400) = 1208 items.
  {
    int4 z = make_int4(0, 0, 0, 0);
    int4* q0 = (int4*)XA0;
    int4* q1 = (int4*)XA1;
#pragma unroll
    for (int it = 0; it < 3; ++it) {
      int g = tid + 512 * it;
      if (g < 1208) {
        int4* q;
        int idx;
        if (g < 408) {
          int bb = g / 204, r = g - bb * 204;
          q = bb ? q1 : q0;
          idx = (100 + r / 17) * 17 + (r % 17);
        } else {
          int r = g - 408;
          int bb = r / 400;
          r -= bb * 400;
          q = bb ? q1 : q0;
          idx = (r >> 2) * 17 + 13 + (r & 3);
        }
        q[idx] = z;
      }
    }
  }

#pragma unroll
  for (int j = 0; j < 7; ++j) UF[tid + 512 * j] = uf[j];
#pragma unroll
  for (int it = 0; it < 3; ++it) {
    int g = tid + 512 * it;
    if (g < 1300) {
      int o = g / 100, n = g - o * 100, k0 = o * 8;
      half8 h;
#pragma unroll
      for (int j = 0; j < 8; ++j) h[j] = (_Float16)xr[it][j];
      *(half8*)&XA0[n * 136 + k0] = h;
    }
  }
  __syncthreads();  // barrier 1: UF + Xr ready

  // ---- P1: issue Xi loads EARLY, then stage-1a (Xr, kt 0..3) ----
  float xi[3][8];
#pragma unroll
  for (int it = 0; it < 3; ++it) {
    int g = tid + 512 * it;
    if (g < 1300) {
      int o = g / 100, n = g - o * 100, k0 = o * 8;
#pragma unroll
      for (int j = 0; j < 8; ++j) {
        int k = k0 + j;
        xi[it][j] = (k < DIM) ? Xim[k * DIM + n] : 0.f;
      }
    }
  }

  floatx4 accR[7], accI[7];
  const floatx4 zz = {0.f, 0.f, 0.f, 0.f};
#pragma unroll
  for (int n = 0; n < 7; ++n) {
    accR[n] = zz;
    accI[n] = zz;
  }
  if (mt < 7) {
#pragma unroll
    for (int ktm = 0; ktm < 4; ++ktm) {
      half8 aR = UF[(mt * 4 + ktm) * 64 + lane];         // Ur
      half8 aI = UF[1792 + (mt * 4 + ktm) * 64 + lane];  // Ui
#pragma unroll
      for (int nt = 0; nt < 7; ++nt) {
        half8 bf =
            *(const half8*)&XA0[(nt * 16 + l16) * 136 + ktm * 32 + quad * 8];
        accR[nt] =
            __builtin_amdgcn_mfma_f32_16x16x32_f16(aR, bf, accR[nt], 0, 0, 0);
        accI[nt] =
            __builtin_amdgcn_mfma_f32_16x16x32_f16(aI, bf, accI[nt], 0, 0, 0);
      }
    }
  }
  // write Xi plane into the OTHER buffer (no overwrite hazard)
#pragma unroll
  for (int it = 0; it < 3; ++it) {
    int g = tid + 512 * it;
    if (g < 1300) {
      int o = g / 100, n = g - o * 100, k0 = o * 8;
      half8 h;
#pragma unroll
      for (int j = 0; j < 8; ++j) h[j] = (_Float16)xi[it][j];
      *(half8*)&XA1[n * 136 + k0] = h;
    }
  }
  __syncthreads();  // barrier 2: Xi ready

  // ---- P2: stage-1b (Xi, kt 4..7): frR = -Ui, frI = Ur ----
  if (mt < 7) {
#pragma unroll
    for (int ktm = 0; ktm < 4; ++ktm) {
      half8 ui = UF[1792 + (mt * 4 + ktm) * 64 + lane];
      half8 ur = UF[(mt * 4 + ktm) * 64 + lane];
      half8 aR = neg_h8(ui);
#pragma unroll
      for (int nt = 0; nt < 7; ++nt) {
        half8 bf =
            *(const half8*)&XA1[(nt * 16 + l16) * 136 + ktm * 32 + quad * 8];
        accR[nt] =
            __builtin_amdgcn_mfma_f32_16x16x32_f16(aR, bf, accR[nt], 0, 0, 0);
        accI[nt] =
            __builtin_amdgcn_mfma_f32_16x16x32_f16(ur, bf, accI[nt], 0, 0, 0);
      }
    }
  }
  __syncthreads();  // barrier 3: all stage-1 reads of XA0/XA1 done

  // ---- A2 writes: Tr -> XA0, Ti -> XA1 (rows 0..111 all covered) ----
  if (mt < 7) {
    int row0 = mt * 16 + quad * 4;
#pragma unroll
    for (int nt = 0; nt < 7; ++nt) {
      int c = nt * 16 + l16;
#pragma unroll
      for (int r = 0; r < 4; ++r) {
        XA0[(row0 + r) * 136 + c] = (_Float16)accR[nt][r];
        XA1[(row0 + r) * 136 + c] = (_Float16)accI[nt][r];
      }
    }
  }
  __syncthreads();  // barrier 4: A2 ready

  // ---- P3: stage-2 out_re = Tr·Ur^T + Ti·Ui^T (pure LDS + MFMA) ----
  floatx4 acc2[7];
#pragma unroll
  for (int n = 0; n < 7; ++n) acc2[n] = zz;
  if (mt < 7) {
    half8 a2r[4], a2i[4];
#pragma unroll
    for (int k2 = 0; k2 < 4; ++k2) {
      a2r[k2] =
          *(const half8*)&XA0[(mt * 16 + l16) * 136 + k2 * 32 + quad * 8];
      a2i[k2] =
          *(const half8*)&XA1[(mt * 16 + l16) * 136 + k2 * 32 + quad * 8];
    }
#pragma unroll
    for (int nt = 0; nt < 7; ++nt) {
#pragma unroll
      for (int k2 = 0; k2 < 4; ++k2) {
        half8 bR = UF[(nt * 4 + k2) * 64 + lane];  // Ur^T frag
        acc2[nt] = __builtin_amdgcn_mfma_f32_16x16x32_f16(a2r[k2], bR,
                                                          acc2[nt], 0, 0, 0);
      }
#pragma unroll
      for (int k2 = 0; k2 < 4; ++k2) {
        half8 bI = UF[1792 + (nt * 4 + k2) * 64 + lane];  // Ui^T frag
        acc2[nt] = __builtin_amdgcn_mfma_f32_16x16x32_f16(a2i[k2], bI,
                                                          acc2[nt], 0, 0, 0);
      }
    }

    // ---- epilogue: real part only, guarded to 100x100 ----
    float* outb = out + (size_t)b * (DIM * DIM);
#pragma unroll
    for (int nt = 0; nt < 7; ++nt) {
      int c = nt * 16 + l16;
      if (c < DIM) {
#pragma unroll
        for (int r = 0; r < 4; ++r) {
          int row = mt * 16 + quad * 4 + r;
          if (row < DIM) outb[row * DIM + c] = acc2[nt][r];
        }
      }
    }
  }
}

extern "C" void kernel_launch(void* const* d_in, const int* in_sizes, int n_in,
                              void* d_out, int out_size, void* d_ws,
                              size_t ws_size, hipStream_t stream) {
  const float* xre = (const float*)d_in[0];
  const float* xim = (const float*)d_in[1];
  const float* theta = (const float*)d_in[2];
  const float* phi = (const float*)d_in[3];
  const float* dphase = (const float*)d_in[4];
  float* out = (float*)d_out;
  (void)d_ws; (void)ws_size; (void)out_size; (void)n_in;

  static bool attr_done = false;
  if (!attr_done) {  // host-side, not a stream op: graph-capture safe
    hipFuncSetAttribute(reinterpret_cast<const void*>(transform_kernel),
                        hipFuncAttributeMaxDynamicSharedMemorySize, 118272);
    attr_done = true;
  }

  hipLaunchKernelGGL(build_U_scan, dim3(25), dim3(256), 0, stream, theta, phi,
                     dphase);
  hipLaunchKernelGGL(pack_kernel, dim3(14), dim3(256), 0, stream);
  const int B = in_sizes[0] / (DIM * DIM);  // 2048
  hipLaunchKernelGGL(transform_kernel, dim3(B), dim3(512), 118272, stream,
                     xre, xim, out);
}